// Round 5
// baseline (1704.067 us; speedup 1.0000x reference)
//
#include <hip/hip_runtime.h>
#include <hip/hip_bf16.h>
#include <math.h>

// Split-bf16 MFMA exact-KNN (K=32) + inverse-squared-distance weighting.
// points:[16384,64] features:[20000,64] targets:[20000] -> out:[16384]
//
// Round 5: 1024 blocks x 512 thr; 16 q/block, 8 waves = 8 m-eighths.
// Subtile-at-a-time register usage (kills AGPR shuttling seen in R3/R4);
// batched 4-value merge-by-rank selection; per-subtile tau refresh.

#define NQ   16384
#define MM   20000
#define DD   64
#define KK   32
#define MPAD 20032
#define NCH  (MPAD / 64)   // 313
#define NW   8

typedef __attribute__((ext_vector_type(8))) short bf16x8;
typedef __attribute__((ext_vector_type(4))) float f32x4;

// ---- workspace layout (bytes) ----
#define OFF_FH 0
#define SZ_FP  (MPAD * DD * 2)
#define OFF_FL (OFF_FH + SZ_FP)
#define OFF_FN (OFF_FL + SZ_FP)
#define SZ_FN  (MPAD * 4)
#define OFF_QH (OFF_FN + SZ_FN)
#define SZ_QP  (NQ * DD * 2)
#define OFF_QL (OFF_QH + SZ_QP)
#define OFF_QN (OFF_QL + SZ_QP)
#define SZ_QN  (NQ * 4)
#define WS_REQ (OFF_QN + SZ_QN)

__device__ __forceinline__ unsigned int bf16_rne(float x) {
    unsigned int xb = __float_as_uint(x);
    return (xb + 0x7fffu + ((xb >> 16) & 1u)) & 0xffff0000u;
}

__global__ void prep_split(const float* __restrict__ src,
                           unsigned short* __restrict__ ph,
                           unsigned short* __restrict__ pl,
                           float* __restrict__ nrm, int nrows_real) {
    const int e = blockIdx.x * 256 + threadIdx.x;
    const int m = e >> 6;
    const int lane = threadIdx.x & 63;
    const bool real = (m < nrows_real);
    float x = real ? src[e] : 0.f;
    unsigned int hb = bf16_rne(x);
    float xh = __uint_as_float(hb);
    unsigned int lb = bf16_rne(x - xh);
    ph[e] = (unsigned short)(hb >> 16);
    pl[e] = (unsigned short)(lb >> 16);
    float s = x * x;
    #pragma unroll
    for (int o = 32; o >= 1; o >>= 1) s += __shfl_xor(s, o);
    if (lane == 0) nrm[m] = real ? s : __builtin_inff();
}

#define CSWAP(a,b,ia,ib) { if (a > b) { float tf=a; a=b; b=tf; int ti=ia; ia=ib; ib=ti; } }

__global__ __launch_bounds__(512) void knn_mfma(
    const unsigned short* __restrict__ Fh, const unsigned short* __restrict__ Fl,
    const float* __restrict__ fn,
    const unsigned short* __restrict__ Qh, const unsigned short* __restrict__ Ql,
    const float* __restrict__ qn,
    const float* __restrict__ targets, float* __restrict__ out)
{
    __shared__ float top_d[NW][16 * 33];
    __shared__ int   top_i[NW][16 * 33];

    const int tid  = threadIdx.x;
    const int lane = tid & 63;
    const int w    = tid >> 6;          // 0..7 = m-eighth
    const int qbase = blockIdx.x * 16;
    const int q    = lane & 15;
    const int hgrp = lane >> 4;

    // init own wave's list (own-wave use only; no sync needed until epilogue)
    for (int i = lane; i < 16 * 33; i += 64) {
        top_d[w][i] = __builtin_inff();
        top_i[w][i] = 0;
    }

    // stationary B-operand (Q^T) fragments
    const int qrow = qbase + q;
    const int kof  = hgrp * 8;
    const bf16x8 qh0 = *(const bf16x8*)(Qh + (size_t)qrow * DD + kof);
    const bf16x8 qh1 = *(const bf16x8*)(Qh + (size_t)qrow * DD + kof + 32);
    const bf16x8 ql0 = *(const bf16x8*)(Ql + (size_t)qrow * DD + kof);
    const bf16x8 ql1 = *(const bf16x8*)(Ql + (size_t)qrow * DD + kof + 32);

    float* myTd = &top_d[w][0];
    int*   myTi = &top_i[w][0];

    for (int c = w; c < NCH; c += NW) {
        const int mbase = c * 64;
        #pragma unroll
        for (int t = 0; t < 4; ++t) {
            const float tau = myTd[q * 33 + 31];   // broadcast, conflict-free

            // one subtile's A-fragments only (keeps peak VGPR low)
            const int frow = mbase + t * 16 + q;
            const unsigned short* ph = Fh + (size_t)frow * DD + kof;
            const unsigned short* pl = Fl + (size_t)frow * DD + kof;
            const bf16x8 Ah0 = *(const bf16x8*)(ph);
            const bf16x8 Ah1 = *(const bf16x8*)(ph + 32);
            const bf16x8 Al0 = *(const bf16x8*)(pl);
            const bf16x8 Al1 = *(const bf16x8*)(pl + 32);
            const f32x4  fnv = *(const f32x4*)(fn + mbase + t * 16 + hgrp * 4);

            f32x4 acc = {0.f, 0.f, 0.f, 0.f};
            acc = __builtin_amdgcn_mfma_f32_16x16x32_bf16(Ah0, qh0, acc, 0, 0, 0);
            acc = __builtin_amdgcn_mfma_f32_16x16x32_bf16(Ah1, qh1, acc, 0, 0, 0);
            acc = __builtin_amdgcn_mfma_f32_16x16x32_bf16(Ah0, ql0, acc, 0, 0, 0);
            acc = __builtin_amdgcn_mfma_f32_16x16x32_bf16(Ah1, ql1, acc, 0, 0, 0);
            acc = __builtin_amdgcn_mfma_f32_16x16x32_bf16(Al0, qh0, acc, 0, 0, 0);
            acc = __builtin_amdgcn_mfma_f32_16x16x32_bf16(Al1, qh1, acc, 0, 0, 0);
            acc = __builtin_amdgcn_mfma_f32_16x16x32_bf16(Al0, ql0, acc, 0, 0, 0);
            acc = __builtin_amdgcn_mfma_f32_16x16x32_bf16(Al1, ql1, acc, 0, 0, 0);

            const float s0 = fnv[0] - 2.f * acc[0];
            const float s1 = fnv[1] - 2.f * acc[1];
            const float s2 = fnv[2] - 2.f * acc[2];
            const float s3 = fnv[3] - 2.f * acc[3];

            const float mn = fminf(fminf(s0, s1), fminf(s2, s3));
            unsigned long long bal = __ballot(mn < tau);
            const int rbase = mbase + t * 16;

            while (bal) {
                const int src = __builtin_ctzll(bal);
                bal &= bal - 1;
                const int qu   = src & 15;
                const int mrow = rbase + (src >> 4) * 4;

                // broadcast the 4 candidate values; sort (stable: idx asc on ties)
                float v0 = __shfl(s0, src), v1 = __shfl(s1, src);
                float v2 = __shfl(s2, src), v3 = __shfl(s3, src);
                int i0 = mrow, i1 = mrow + 1, i2 = mrow + 2, i3 = mrow + 3;
                CSWAP(v0, v1, i0, i1); CSWAP(v2, v3, i2, i3);
                CSWAP(v0, v2, i0, i2); CSWAP(v1, v3, i1, i3);
                CSWAP(v1, v2, i1, i2);

                const int sl   = lane & 31;
                const int base = qu * 33;
                const float od = myTd[base + sl];
                const int   oi = myTi[base + sl];

                // old element's shift = #new strictly before it
                const int cnt = (int)(v0 < od) + (int)(v1 < od) + (int)(v2 < od) + (int)(v3 < od);
                // new elements' ranks: #old <= v_j (old-before-new on ties) + j
                const int p0 = __popc((unsigned)__ballot(od <= v0));
                const int p1 = __popc((unsigned)__ballot(od <= v1));
                const int p2 = __popc((unsigned)__ballot(od <= v2));
                const int p3 = __popc((unsigned)__ballot(od <= v3));

                const int tdst = sl + cnt;
                if (lane < 32 && tdst < 32) {
                    myTd[base + tdst] = od;
                    myTi[base + tdst] = oi;
                }
                const int r0 = p0 + 0, r1 = p1 + 1, r2 = p2 + 2, r3 = p3 + 3;
                const float wv = (lane == 0) ? v0 : (lane == 1) ? v1 : (lane == 2) ? v2 : v3;
                const int   wi = (lane == 0) ? i0 : (lane == 1) ? i1 : (lane == 2) ? i2 : i3;
                const int   wr = (lane == 0) ? r0 : (lane == 1) ? r1 : (lane == 2) ? r2 : r3;
                if (lane < 4 && wr < 32) {
                    myTd[base + wr] = wv;
                    myTi[base + wr] = wi;
                }
            }
        }
    }

    __syncthreads();

    // ============ epilogue: 8-way merge by rank, weight, reduce ============
    // wave w handles queries 2w, 2w+1; lane -> list l=lane>>3, slots (lane&7)+{0,8,16,24}
    const int l  = lane >> 3;
    const int sb = lane & 7;
    #pragma unroll
    for (int e = 0; e < 2; ++e) {
        const int qq = w * 2 + e;
        const int qglob = qbase + qq;
        const float qnv = qn[qglob];
        float nume = 0.f, deno = 0.f;
        #pragma unroll
        for (int ss = 0; ss < 4; ++ss) {
            const int slot = sb + ss * 8;
            const float v  = top_d[l][qq * 33 + slot];
            const int   mi = top_i[l][qq * 33 + slot];
            int rank = slot;
            #pragma unroll
            for (int jj = 0; jj < NW; ++jj) {
                if (jj == l) continue;
                int cnt = 0;
                #pragma unroll
                for (int st = 32; st >= 1; st >>= 1) {
                    const int t2 = cnt + st;
                    if (t2 <= 32) {
                        const float dj = top_d[jj][qq * 33 + t2 - 1];
                        const int   ij = top_i[jj][qq * 33 + t2 - 1];
                        if (dj < v || (dj == v && ij < mi)) cnt = t2;
                    }
                }
                rank += cnt;
            }
            if (rank < KK) {
                const float d2 = fmaxf(qnv + v, 0.f);
                const float wv = 1.f / (d2 + 1e-4f);
                nume = fmaf(wv, targets[mi], nume);
                deno += wv;
            }
        }
        #pragma unroll
        for (int o = 32; o >= 1; o >>= 1) {
            nume += __shfl_xor(nume, o);
            deno += __shfl_xor(deno, o);
        }
        if (lane == 0) out[qglob] = nume / fmaxf(deno, 1e-9f);
    }
}

// ---------------- fallback: round-1 exact fp32 vector kernel ----------------
#define BQ 32
#define WQ 8
__global__ __launch_bounds__(256) void hp_knn_kernel(
    const float* __restrict__ points, const float* __restrict__ features,
    const float* __restrict__ targets, float* __restrict__ out)
{
    __shared__ __align__(16) float Qs[BQ][DD];
    __shared__ float qn_s[BQ];
    __shared__ float topd[BQ][KK];
    __shared__ int   topi[BQ][KK];
    const int tid = threadIdx.x, lane = tid & 63, wv = tid >> 6, qb = wv * WQ;
    {
        const float4* src = (const float4*)(points + (size_t)blockIdx.x * BQ * DD);
        float4* dst = (float4*)&Qs[0][0];
        #pragma unroll
        for (int i = 0; i < (BQ * DD / 4) / 256; ++i) dst[tid + i * 256] = src[tid + i * 256];
    }
    for (int i = tid; i < BQ * KK; i += 256) { (&topd[0][0])[i] = __builtin_inff(); (&topi[0][0])[i] = 0; }
    __syncthreads();
    if (tid < BQ) {
        float s = 0.f;
        #pragma unroll
        for (int d = 0; d < DD; ++d) s = fmaf(Qs[tid][d], Qs[tid][d], s);
        qn_s[tid] = s;
    }
    __syncthreads();
    for (int c = 0; c < (MM + 63) / 64; ++c) {
        const int m = c * 64 + lane, mc = (m < MM) ? m : (MM - 1);
        float f[DD];
        const float4* fr = (const float4*)(features + (size_t)mc * DD);
        #pragma unroll
        for (int b = 0; b < DD / 4; ++b) { float4 v = fr[b]; f[4*b]=v.x; f[4*b+1]=v.y; f[4*b+2]=v.z; f[4*b+3]=v.w; }
        float fnv = 0.f;
        #pragma unroll
        for (int d = 0; d < DD; ++d) fnv = fmaf(f[d], f[d], fnv);
        float d2v[WQ];
        #pragma unroll
        for (int qi = 0; qi < WQ; ++qi) {
            const float4* qr = (const float4*)&Qs[qb + qi][0];
            float a0=0,a1=0,a2=0,a3=0;
            #pragma unroll
            for (int b = 0; b < DD / 4; ++b) {
                float4 q4 = qr[b];
                a0 = fmaf(q4.x, f[4*b], a0); a1 = fmaf(q4.y, f[4*b+1], a1);
                a2 = fmaf(q4.z, f[4*b+2], a2); a3 = fmaf(q4.w, f[4*b+3], a3);
            }
            float d2 = fmaxf(qn_s[qb+qi] + fnv - 2.f*((a0+a1)+(a2+a3)), 0.f);
            d2v[qi] = (m < MM) ? d2 : __builtin_inff();
        }
        #pragma unroll
        for (int qi = 0; qi < WQ; ++qi) {
            const int q = qb + qi;
            unsigned long long ball = __ballot(d2v[qi] < topd[q][KK-1]);
            while (ball) {
                const int j = __builtin_ctzll(ball); ball &= ball - 1;
                const float dval = __shfl(d2v[qi], j); const int mval = c * 64 + j;
                if (lane < KK) {
                    const float cur = topd[q][lane];
                    if (cur > dval) {
                        const float pd = (lane > 0) ? topd[q][lane-1] : -1.f;
                        const int   pi = (lane > 0) ? topi[q][lane-1] : 0;
                        const bool tp = (pd > dval);
                        topd[q][lane] = tp ? pd : dval; topi[q][lane] = tp ? pi : mval;
                    }
                }
            }
        }
    }
    #pragma unroll
    for (int qi = 0; qi < WQ; ++qi) {
        const int q = qb + qi;
        float wsum = 0.f, wt = 0.f;
        if (lane < KK) {
            const float ww = 1.f / (topd[q][lane] + 1e-4f);
            wsum = ww; wt = ww * targets[topi[q][lane]];
        }
        #pragma unroll
        for (int o = 32; o >= 1; o >>= 1) { wsum += __shfl_xor(wsum, o); wt += __shfl_xor(wt, o); }
        if (lane == 0) out[(size_t)blockIdx.x * BQ + q] = wt / fmaxf(wsum, 1e-9f);
    }
}

extern "C" void kernel_launch(void* const* d_in, const int* in_sizes, int n_in,
                              void* d_out, int out_size, void* d_ws, size_t ws_size,
                              hipStream_t stream) {
    const float* points   = (const float*)d_in[0];
    const float* features = (const float*)d_in[1];
    const float* targets  = (const float*)d_in[2];
    float* out = (float*)d_out;

    if (ws_size < (size_t)WS_REQ) {
        hp_knn_kernel<<<dim3(NQ / BQ), dim3(256), 0, stream>>>(points, features, targets, out);
        return;
    }
    char* ws = (char*)d_ws;
    unsigned short* Fh = (unsigned short*)(ws + OFF_FH);
    unsigned short* Fl = (unsigned short*)(ws + OFF_FL);
    float*          fn = (float*)(ws + OFF_FN);
    unsigned short* Qh = (unsigned short*)(ws + OFF_QH);
    unsigned short* Ql = (unsigned short*)(ws + OFF_QL);
    float*          qnp= (float*)(ws + OFF_QN);

    prep_split<<<dim3(MPAD * DD / 256), dim3(256), 0, stream>>>(features, Fh, Fl, fn, MM);
    prep_split<<<dim3(NQ * DD / 256),  dim3(256), 0, stream>>>(points,   Qh, Ql, qnp, NQ);
    knn_mfma<<<dim3(NQ / 16), dim3(512), 0, stream>>>(Fh, Fl, fn, Qh, Ql, qnp, targets, out);
}

// Round 6
// 707.655 us; speedup vs baseline: 2.4080x; 2.4080x over previous
//
#include <hip/hip_runtime.h>
#include <hip/hip_bf16.h>
#include <math.h>

// Split-bf16 MFMA exact-KNN (K=32) + inverse-squared-distance weighting.
// points:[16384,64] features:[20000,64] targets:[20000] -> out:[16384]
//
// Round 6: filter-then-rank. Phase 1: 2048-row sample -> per-query tau
// (u16-key count-select; tau >= true 32nd since sample 32nd >= full 32nd).
// Phase 2: full scan, append s<=tau candidates to LDS buffer (no sorted
// lists, no LDS reads in the MFMA loop). Phase 3: exact bit-descent rank
// over candidates, top_k-compatible index tie-break, weighted sum.

#define NQ   16384
#define MM   20000
#define DD   64
#define KK   32
#define MPAD 20032
#define NCH  (MPAD / 64)   // 313
#define NW   8
#define CAP  768
#define SMPN 2048          // sample rows = chunks 0..31

typedef __attribute__((ext_vector_type(8))) short bf16x8;
typedef __attribute__((ext_vector_type(4))) float f32x4;

// ---- workspace layout (bytes) ----
#define OFF_FH 0
#define SZ_FP  (MPAD * DD * 2)
#define OFF_FL (OFF_FH + SZ_FP)
#define OFF_FN (OFF_FL + SZ_FP)
#define SZ_FN  (MPAD * 4)
#define OFF_QH (OFF_FN + SZ_FN)
#define SZ_QP  (NQ * DD * 2)
#define OFF_QL (OFF_QH + SZ_QP)
#define OFF_QN (OFF_QL + SZ_QP)
#define SZ_QN  (NQ * 4)
#define WS_REQ (OFF_QN + SZ_QN)

__device__ __forceinline__ unsigned int bf16_rne(float x) {
    unsigned int xb = __float_as_uint(x);
    return (xb + 0x7fffu + ((xb >> 16) & 1u)) & 0xffff0000u;
}
__device__ __forceinline__ unsigned enc32(float f) {
    unsigned b = __float_as_uint(f);
    return (b & 0x80000000u) ? ~b : (b | 0x80000000u);
}
__device__ __forceinline__ float dec32(unsigned k) {
    unsigned b = (k & 0x80000000u) ? (k & 0x7FFFFFFFu) : ~k;
    return __uint_as_float(b);
}

__global__ void prep_split(const float* __restrict__ src,
                           unsigned short* __restrict__ ph,
                           unsigned short* __restrict__ pl,
                           float* __restrict__ nrm, int nrows_real) {
    const int e = blockIdx.x * 256 + threadIdx.x;
    const int m = e >> 6;
    const int lane = threadIdx.x & 63;
    const bool real = (m < nrows_real);
    float x = real ? src[e] : 0.f;
    unsigned int hb = bf16_rne(x);
    float xh = __uint_as_float(hb);
    unsigned int lb = bf16_rne(x - xh);
    ph[e] = (unsigned short)(hb >> 16);
    pl[e] = (unsigned short)(lb >> 16);
    float s = x * x;
    #pragma unroll
    for (int o = 32; o >= 1; o >>= 1) s += __shfl_xor(s, o);
    if (lane == 0) nrm[m] = real ? s : __builtin_inff();
}

// computes s0..s3 for one 16-row subtile via 4-term split-bf16 (exact-grade)
#define SUBTILE_S(mbase_, t_)                                                   \
    const int frow = (mbase_) + (t_) * 16 + q;                                  \
    const unsigned short* phh = Fh + (size_t)frow * DD + kof;                   \
    const unsigned short* pll = Fl + (size_t)frow * DD + kof;                   \
    const bf16x8 Ah0 = *(const bf16x8*)(phh);                                   \
    const bf16x8 Ah1 = *(const bf16x8*)(phh + 32);                              \
    const bf16x8 Al0 = *(const bf16x8*)(pll);                                   \
    const bf16x8 Al1 = *(const bf16x8*)(pll + 32);                              \
    const f32x4  fnv = *(const f32x4*)(fn + (mbase_) + (t_) * 16 + hgrp * 4);   \
    f32x4 acc = {0.f, 0.f, 0.f, 0.f};                                           \
    acc = __builtin_amdgcn_mfma_f32_16x16x32_bf16(Ah0, qh0, acc, 0, 0, 0);      \
    acc = __builtin_amdgcn_mfma_f32_16x16x32_bf16(Ah1, qh1, acc, 0, 0, 0);      \
    acc = __builtin_amdgcn_mfma_f32_16x16x32_bf16(Ah0, ql0, acc, 0, 0, 0);      \
    acc = __builtin_amdgcn_mfma_f32_16x16x32_bf16(Ah1, ql1, acc, 0, 0, 0);      \
    acc = __builtin_amdgcn_mfma_f32_16x16x32_bf16(Al0, qh0, acc, 0, 0, 0);      \
    acc = __builtin_amdgcn_mfma_f32_16x16x32_bf16(Al1, qh1, acc, 0, 0, 0);      \
    acc = __builtin_amdgcn_mfma_f32_16x16x32_bf16(Al0, ql0, acc, 0, 0, 0);      \
    acc = __builtin_amdgcn_mfma_f32_16x16x32_bf16(Al1, ql1, acc, 0, 0, 0);      \
    const float s0 = fnv[0] - 2.f * acc[0];                                     \
    const float s1 = fnv[1] - 2.f * acc[1];                                     \
    const float s2 = fnv[2] - 2.f * acc[2];                                     \
    const float s3 = fnv[3] - 2.f * acc[3];

__global__ __launch_bounds__(512) void knn_filter(
    const unsigned short* __restrict__ Fh, const unsigned short* __restrict__ Fl,
    const float* __restrict__ fn,
    const unsigned short* __restrict__ Qh, const unsigned short* __restrict__ Ql,
    const float* __restrict__ qn,
    const float* __restrict__ targets, float* __restrict__ out)
{
    // pool: phase1 = smp u16[16][2048] (64KB); phase2/3 = buf_d f32[16][CAP]
    // (48KB) followed by buf_i u16[16][CAP] (24KB). 73728 B total.
    __shared__ __align__(16) unsigned char pool[16 * CAP * 6];
    __shared__ float tau_f[16];
    __shared__ int   cnt[16];

    unsigned short* smp  = (unsigned short*)pool;
    float*          bufd = (float*)pool;
    unsigned short* bufi = (unsigned short*)(pool + 16 * CAP * 4);

    const int tid  = threadIdx.x;
    const int lane = tid & 63;
    const int w    = tid >> 6;          // 0..7
    const int qbase = blockIdx.x * 16;
    const int q    = lane & 15;
    const int hgrp = lane >> 4;

    if (tid < 16) cnt[tid] = 0;

    // stationary B-operand (Q^T) fragments
    const int qrow = qbase + q;
    const int kof  = hgrp * 8;
    const bf16x8 qh0 = *(const bf16x8*)(Qh + (size_t)qrow * DD + kof);
    const bf16x8 qh1 = *(const bf16x8*)(Qh + (size_t)qrow * DD + kof + 32);
    const bf16x8 ql0 = *(const bf16x8*)(Ql + (size_t)qrow * DD + kof);
    const bf16x8 ql1 = *(const bf16x8*)(Ql + (size_t)qrow * DD + kof + 32);

    // ================= phase 1: sample -> u16 keys in LDS =================
    #pragma unroll
    for (int cc = 0; cc < 4; ++cc) {
        const int mbase = (w * 4 + cc) * 64;
        #pragma unroll
        for (int t = 0; t < 4; ++t) {
            SUBTILE_S(mbase, t)
            const int rbase = mbase + t * 16 + hgrp * 4;   // == sample index
            smp[q * SMPN + rbase + 0] = (unsigned short)(enc32(s0) >> 16);
            smp[q * SMPN + rbase + 1] = (unsigned short)(enc32(s1) >> 16);
            smp[q * SMPN + rbase + 2] = (unsigned short)(enc32(s2) >> 16);
            smp[q * SMPN + rbase + 3] = (unsigned short)(enc32(s3) >> 16);
        }
    }
    __syncthreads();

    // tau search: wave w handles queries 2w, 2w+1
    #pragma unroll
    for (int e = 0; e < 2; ++e) {
        const int q2 = w * 2 + e;
        unsigned short vv[32];
        #pragma unroll
        for (int u = 0; u < 32; ++u) vv[u] = smp[q2 * SMPN + lane + u * 64];
        unsigned lo = 0;
        #pragma unroll
        for (int bit = 15; bit >= 0; --bit) {
            const unsigned trial = lo | (1u << bit);
            int c = 0;
            #pragma unroll
            for (int u = 0; u < 32; ++u) c += (vv[u] < trial);
            #pragma unroll
            for (int o = 32; o >= 1; o >>= 1) c += __shfl_xor(c, o);
            if (c < KK) lo = trial;
        }
        // upper edge of the 32nd key's bin: covers all floats in that bin
        const float tf = (lo >= 0xFFFFu) ? __builtin_inff()
                                         : dec32((lo + 1u) << 16);
        if (lane == 0) tau_f[q2] = tf;
    }
    __syncthreads();   // smp dead after this; buffers take over the pool

    // ================= phase 2: full scan, append candidates ==============
    const float tauR = tau_f[q];
    for (int c = w; c < NCH; c += NW) {
        const int mbase = c * 64;
        #pragma unroll
        for (int t = 0; t < 4; ++t) {
            SUBTILE_S(mbase, t)
            const int rbase = mbase + t * 16 + hgrp * 4;
            const float sv[4] = {s0, s1, s2, s3};
            #pragma unroll
            for (int j = 0; j < 4; ++j) {
                if (sv[j] <= tauR) {
                    const int p = atomicAdd(&cnt[q], 1);
                    if (p < CAP) {
                        bufd[q * CAP + p] = sv[j];
                        bufi[q * CAP + p] = (unsigned short)(rbase + j);
                    }
                }
            }
        }
    }
    __syncthreads();

    // ================= phase 3: exact rank + weighted sum =================
    #pragma unroll
    for (int e = 0; e < 2; ++e) {
        const int q3 = w * 2 + e;
        const int n  = min(cnt[q3], CAP);
        const float qnv = qn[qbase + q3];

        // owned slots j = lane + u*64, fixed U=12 (covers CAP=768)
        float    ms[12]; unsigned kk[12]; unsigned short miu[12];
        #pragma unroll
        for (int u = 0; u < 12; ++u) {
            const int j = lane + u * 64;
            const bool v = (j < n);
            ms[u]  = v ? bufd[q3 * CAP + j] : __builtin_inff();
            miu[u] = v ? bufi[q3 * CAP + j] : (unsigned short)0xFFFFu;
            kk[u]  = enc32(ms[u]);
        }
        // 32-bit bit-descent: theta = key of 32nd smallest s
        unsigned lo = 0;
        for (int bit = 31; bit >= 0; --bit) {
            const unsigned trial = lo | (1u << bit);
            int c = 0;
            #pragma unroll
            for (int u = 0; u < 12; ++u) c += (kk[u] < trial);
            #pragma unroll
            for (int o = 32; o >= 1; o >>= 1) c += __shfl_xor(c, o);
            if (c < KK) lo = trial;
        }
        // tie resolution by smallest index (matches top_k order)
        int c0 = 0, tcnt = 0;
        #pragma unroll
        for (int u = 0; u < 12; ++u) { c0 += (kk[u] < lo); tcnt += (kk[u] == lo); }
        #pragma unroll
        for (int o = 32; o >= 1; o >>= 1) {
            c0 += __shfl_xor(c0, o); tcnt += __shfl_xor(tcnt, o);
        }
        const int kprime = KK - c0;
        unsigned ilo = 0xFFFFu;
        if (tcnt != kprime) {
            ilo = 0;
            for (int bit = 15; bit >= 0; --bit) {
                const unsigned trial = ilo | (1u << bit);
                int c = 0;
                #pragma unroll
                for (int u = 0; u < 12; ++u)
                    c += ((kk[u] == lo) && ((unsigned)miu[u] < trial));
                #pragma unroll
                for (int o = 32; o >= 1; o >>= 1) c += __shfl_xor(c, o);
                if (c < kprime) ilo = trial;
            }
        }
        float nume = 0.f, deno = 0.f;
        #pragma unroll
        for (int u = 0; u < 12; ++u) {
            const bool inc = (kk[u] < lo) ||
                             ((kk[u] == lo) && ((unsigned)miu[u] <= ilo));
            if (inc) {
                const float d2 = fmaxf(qnv + ms[u], 0.f);
                const float wv = 1.f / (d2 + 1e-4f);
                nume = fmaf(wv, targets[miu[u]], nume);
                deno += wv;
            }
        }
        #pragma unroll
        for (int o = 32; o >= 1; o >>= 1) {
            nume += __shfl_xor(nume, o);
            deno += __shfl_xor(deno, o);
        }
        if (lane == 0) out[qbase + q3] = nume / fmaxf(deno, 1e-9f);
    }
}

// ---------------- fallback: round-1 exact fp32 vector kernel ----------------
#define BQ 32
#define WQ 8
__global__ __launch_bounds__(256) void hp_knn_kernel(
    const float* __restrict__ points, const float* __restrict__ features,
    const float* __restrict__ targets, float* __restrict__ out)
{
    __shared__ __align__(16) float Qs[BQ][DD];
    __shared__ float qn_s[BQ];
    __shared__ float topd[BQ][KK];
    __shared__ int   topi[BQ][KK];
    const int tid = threadIdx.x, lane = tid & 63, wv = tid >> 6, qb = wv * WQ;
    {
        const float4* src = (const float4*)(points + (size_t)blockIdx.x * BQ * DD);
        float4* dst = (float4*)&Qs[0][0];
        #pragma unroll
        for (int i = 0; i < (BQ * DD / 4) / 256; ++i) dst[tid + i * 256] = src[tid + i * 256];
    }
    for (int i = tid; i < BQ * KK; i += 256) { (&topd[0][0])[i] = __builtin_inff(); (&topi[0][0])[i] = 0; }
    __syncthreads();
    if (tid < BQ) {
        float s = 0.f;
        #pragma unroll
        for (int d = 0; d < DD; ++d) s = fmaf(Qs[tid][d], Qs[tid][d], s);
        qn_s[tid] = s;
    }
    __syncthreads();
    for (int c = 0; c < (MM + 63) / 64; ++c) {
        const int m = c * 64 + lane, mc = (m < MM) ? m : (MM - 1);
        float f[DD];
        const float4* fr = (const float4*)(features + (size_t)mc * DD);
        #pragma unroll
        for (int b = 0; b < DD / 4; ++b) { float4 v = fr[b]; f[4*b]=v.x; f[4*b+1]=v.y; f[4*b+2]=v.z; f[4*b+3]=v.w; }
        float fnv = 0.f;
        #pragma unroll
        for (int d = 0; d < DD; ++d) fnv = fmaf(f[d], f[d], fnv);
        float d2v[WQ];
        #pragma unroll
        for (int qi = 0; qi < WQ; ++qi) {
            const float4* qr = (const float4*)&Qs[qb + qi][0];
            float a0=0,a1=0,a2=0,a3=0;
            #pragma unroll
            for (int b = 0; b < DD / 4; ++b) {
                float4 q4 = qr[b];
                a0 = fmaf(q4.x, f[4*b], a0); a1 = fmaf(q4.y, f[4*b+1], a1);
                a2 = fmaf(q4.z, f[4*b+2], a2); a3 = fmaf(q4.w, f[4*b+3], a3);
            }
            float d2 = fmaxf(qn_s[qb+qi] + fnv - 2.f*((a0+a1)+(a2+a3)), 0.f);
            d2v[qi] = (m < MM) ? d2 : __builtin_inff();
        }
        #pragma unroll
        for (int qi = 0; qi < WQ; ++qi) {
            const int q = qb + qi;
            unsigned long long ball = __ballot(d2v[qi] < topd[q][KK-1]);
            while (ball) {
                const int j = __builtin_ctzll(ball); ball &= ball - 1;
                const float dval = __shfl(d2v[qi], j); const int mval = c * 64 + j;
                if (lane < KK) {
                    const float cur = topd[q][lane];
                    if (cur > dval) {
                        const float pd = (lane > 0) ? topd[q][lane-1] : -1.f;
                        const int   pi = (lane > 0) ? topi[q][lane-1] : 0;
                        const bool tp = (pd > dval);
                        topd[q][lane] = tp ? pd : dval; topi[q][lane] = tp ? pi : mval;
                    }
                }
            }
        }
    }
    #pragma unroll
    for (int qi = 0; qi < WQ; ++qi) {
        const int q = qb + qi;
        float wsum = 0.f, wt = 0.f;
        if (lane < KK) {
            const float ww = 1.f / (topd[q][lane] + 1e-4f);
            wsum = ww; wt = ww * targets[topi[q][lane]];
        }
        #pragma unroll
        for (int o = 32; o >= 1; o >>= 1) { wsum += __shfl_xor(wsum, o); wt += __shfl_xor(wt, o); }
        if (lane == 0) out[(size_t)blockIdx.x * BQ + q] = wt / fmaxf(wsum, 1e-9f);
    }
}

extern "C" void kernel_launch(void* const* d_in, const int* in_sizes, int n_in,
                              void* d_out, int out_size, void* d_ws, size_t ws_size,
                              hipStream_t stream) {
    const float* points   = (const float*)d_in[0];
    const float* features = (const float*)d_in[1];
    const float* targets  = (const float*)d_in[2];
    float* out = (float*)d_out;

    if (ws_size < (size_t)WS_REQ) {
        hp_knn_kernel<<<dim3(NQ / BQ), dim3(256), 0, stream>>>(points, features, targets, out);
        return;
    }
    char* ws = (char*)d_ws;
    unsigned short* Fh = (unsigned short*)(ws + OFF_FH);
    unsigned short* Fl = (unsigned short*)(ws + OFF_FL);
    float*          fn = (float*)(ws + OFF_FN);
    unsigned short* Qh = (unsigned short*)(ws + OFF_QH);
    unsigned short* Ql = (unsigned short*)(ws + OFF_QL);
    float*          qnp= (float*)(ws + OFF_QN);

    prep_split<<<dim3(MPAD * DD / 256), dim3(256), 0, stream>>>(features, Fh, Fl, fn, MM);
    prep_split<<<dim3(NQ * DD / 256),  dim3(256), 0, stream>>>(points,   Qh, Ql, qnp, NQ);
    knn_filter<<<dim3(NQ / 16), dim3(512), 0, stream>>>(Fh, Fl, fn, Qh, Ql, qnp, targets, out);
}

// Round 7
// 681.129 us; speedup vs baseline: 2.5018x; 1.0389x over previous
//
#include <hip/hip_runtime.h>
#include <hip/hip_bf16.h>
#include <math.h>

// Split-bf16 MFMA exact-KNN (K=32) + inverse-squared-distance weighting.
// points:[16384,64] features:[20000,64] targets:[20000] -> out:[16384]
//
// Round 7: filter-then-rank (R6 structure) + latency fixes:
//  - explicit 2-deep register software pipeline for the feature stream
//  - two independent MFMA accumulator chains (ILP 2, same s in ph1/ph2)
//  - padded sample stride (2056) + ushort4 key writes (bank-conflict-free)
//  - __launch_bounds__(512,4) pins VGPR<=128 so 2 blocks/CU keep 4 waves/SIMD

#define NQ   16384
#define MM   20000
#define DD   64
#define KK   32
#define MPAD 20032
#define NCH  (MPAD / 64)   // 313
#define NW   8
#define CAP  768
#define SMPN 2048          // sample rows = chunks 0..31
#define SMPS 2056          // padded stride (u16) -> conflict-free writes

typedef __attribute__((ext_vector_type(8))) short bf16x8;
typedef __attribute__((ext_vector_type(4))) float f32x4;

// ---- workspace layout (bytes) ----
#define OFF_FH 0
#define SZ_FP  (MPAD * DD * 2)
#define OFF_FL (OFF_FH + SZ_FP)
#define OFF_FN (OFF_FL + SZ_FP)
#define SZ_FN  (MPAD * 4)
#define OFF_QH (OFF_FN + SZ_FN)
#define SZ_QP  (NQ * DD * 2)
#define OFF_QL (OFF_QH + SZ_QP)
#define OFF_QN (OFF_QL + SZ_QP)
#define SZ_QN  (NQ * 4)
#define WS_REQ (OFF_QN + SZ_QN)

__device__ __forceinline__ unsigned int bf16_rne(float x) {
    unsigned int xb = __float_as_uint(x);
    return (xb + 0x7fffu + ((xb >> 16) & 1u)) & 0xffff0000u;
}
__device__ __forceinline__ unsigned enc32(float f) {
    unsigned b = __float_as_uint(f);
    return (b & 0x80000000u) ? ~b : (b | 0x80000000u);
}
__device__ __forceinline__ float dec32(unsigned k) {
    unsigned b = (k & 0x80000000u) ? (k & 0x7FFFFFFFu) : ~k;
    return __uint_as_float(b);
}

__global__ void prep_split(const float* __restrict__ src,
                           unsigned short* __restrict__ ph,
                           unsigned short* __restrict__ pl,
                           float* __restrict__ nrm, int nrows_real) {
    const int e = blockIdx.x * 256 + threadIdx.x;
    const int m = e >> 6;
    const int lane = threadIdx.x & 63;
    const bool real = (m < nrows_real);
    float x = real ? src[e] : 0.f;
    unsigned int hb = bf16_rne(x);
    float xh = __uint_as_float(hb);
    unsigned int lb = bf16_rne(x - xh);
    ph[e] = (unsigned short)(hb >> 16);
    pl[e] = (unsigned short)(lb >> 16);
    float s = x * x;
    #pragma unroll
    for (int o = 32; o >= 1; o >>= 1) s += __shfl_xor(s, o);
    if (lane == 0) nrm[m] = real ? s : __builtin_inff();
}

// ---- load one 16-row subtile's fragments into register bundle P ----
#define LOAD_SUB(P, ci, tt) {                                            \
    const int rb_ = (ci) * 64 + (tt) * 16;                               \
    const unsigned short* ph_ = Fh + (size_t)(rb_ + q) * DD + kof;       \
    const unsigned short* pl_ = Fl + (size_t)(rb_ + q) * DD + kof;       \
    P##h0 = *(const bf16x8*)(ph_);                                       \
    P##h1 = *(const bf16x8*)(ph_ + 32);                                  \
    P##l0 = *(const bf16x8*)(pl_);                                       \
    P##l1 = *(const bf16x8*)(pl_ + 32);                                  \
    P##fn = *(const f32x4*)(fn + rb_ + hgrp * 4);                        \
    P##rb = rb_;                                                         \
}

// ---- 8 MFMA in two independent chains; defines s0..s3, rb4 ----
#define MFMA_CORE(P)                                                        \
    f32x4 accA = {0.f,0.f,0.f,0.f}, accB = {0.f,0.f,0.f,0.f};               \
    accA = __builtin_amdgcn_mfma_f32_16x16x32_bf16(P##h0, qh0, accA,0,0,0); \
    accB = __builtin_amdgcn_mfma_f32_16x16x32_bf16(P##h0, ql0, accB,0,0,0); \
    accA = __builtin_amdgcn_mfma_f32_16x16x32_bf16(P##h1, qh1, accA,0,0,0); \
    accB = __builtin_amdgcn_mfma_f32_16x16x32_bf16(P##h1, ql1, accB,0,0,0); \
    accA = __builtin_amdgcn_mfma_f32_16x16x32_bf16(P##l0, qh0, accA,0,0,0); \
    accB = __builtin_amdgcn_mfma_f32_16x16x32_bf16(P##l0, ql0, accB,0,0,0); \
    accA = __builtin_amdgcn_mfma_f32_16x16x32_bf16(P##l1, qh1, accA,0,0,0); \
    accB = __builtin_amdgcn_mfma_f32_16x16x32_bf16(P##l1, ql1, accB,0,0,0); \
    const float s0 = P##fn[0] - 2.f * (accA[0] + accB[0]);                  \
    const float s1 = P##fn[1] - 2.f * (accA[1] + accB[1]);                  \
    const float s2 = P##fn[2] - 2.f * (accA[2] + accB[2]);                  \
    const float s3 = P##fn[3] - 2.f * (accA[3] + accB[3]);                  \
    const int rb4 = P##rb + hgrp * 4;

#define KEYS_P1 {                                                        \
    ushort4 kv_;                                                         \
    kv_.x = (unsigned short)(enc32(s0) >> 16);                           \
    kv_.y = (unsigned short)(enc32(s1) >> 16);                           \
    kv_.z = (unsigned short)(enc32(s2) >> 16);                           \
    kv_.w = (unsigned short)(enc32(s3) >> 16);                           \
    *(ushort4*)&smp[q * SMPS + rb4] = kv_;                               \
}

#define GATE_P2 {                                                        \
    const float sv_[4] = {s0, s1, s2, s3};                               \
    _Pragma("unroll")                                                    \
    for (int j_ = 0; j_ < 4; ++j_) {                                     \
        if (sv_[j_] <= tauR) {                                           \
            const int p_ = atomicAdd(&cnt[q], 1);                        \
            if (p_ < CAP) {                                              \
                bufd[q * CAP + p_] = sv_[j_];                            \
                bufi[q * CAP + p_] = (unsigned short)(rb4 + j_);         \
            }                                                            \
        }                                                                \
    }                                                                    \
}

__global__ __launch_bounds__(512, 4) void knn_filter(
    const unsigned short* __restrict__ Fh, const unsigned short* __restrict__ Fl,
    const float* __restrict__ fn,
    const unsigned short* __restrict__ Qh, const unsigned short* __restrict__ Ql,
    const float* __restrict__ qn,
    const float* __restrict__ targets, float* __restrict__ out)
{
    // pool: phase1 = smp u16[16][SMPS] (65.8KB); phase2/3 = buf_d f32[16][CAP]
    // (48KB) + buf_i u16[16][CAP] (24KB). 73728 B total.
    __shared__ __align__(16) unsigned char pool[16 * CAP * 6];
    __shared__ float tau_f[16];
    __shared__ int   cnt[16];

    unsigned short* smp  = (unsigned short*)pool;
    float*          bufd = (float*)pool;
    unsigned short* bufi = (unsigned short*)(pool + 16 * CAP * 4);

    const int tid  = threadIdx.x;
    const int lane = tid & 63;
    const int w    = tid >> 6;          // 0..7
    const int qbase = blockIdx.x * 16;
    const int q    = lane & 15;
    const int hgrp = lane >> 4;

    if (tid < 16) cnt[tid] = 0;

    // stationary B-operand (Q^T) fragments
    const int qrow = qbase + q;
    const int kof  = hgrp * 8;
    const bf16x8 qh0 = *(const bf16x8*)(Qh + (size_t)qrow * DD + kof);
    const bf16x8 qh1 = *(const bf16x8*)(Qh + (size_t)qrow * DD + kof + 32);
    const bf16x8 ql0 = *(const bf16x8*)(Ql + (size_t)qrow * DD + kof);
    const bf16x8 ql1 = *(const bf16x8*)(Ql + (size_t)qrow * DD + kof + 32);

    // pipeline register bundles
    bf16x8 Ah0, Ah1, Al0, Al1; f32x4 Afn; int Arb;
    bf16x8 Bh0, Bh1, Bl0, Bl1; f32x4 Bfn; int Brb;

    // ================= phase 1: sample (chunks w*4..w*4+3) -> keys ========
    LOAD_SUB(A, w * 4, 0)
    LOAD_SUB(B, w * 4, 1)
    for (int i = 0; i + 3 < 16; i += 2) {
        { MFMA_CORE(A) KEYS_P1 }
        { const int ii = i + 2; LOAD_SUB(A, w * 4 + (ii >> 2), ii & 3) }
        { MFMA_CORE(B) KEYS_P1 }
        { const int ii = i + 3; LOAD_SUB(B, w * 4 + (ii >> 2), ii & 3) }
    }
    { MFMA_CORE(A) KEYS_P1 }
    { MFMA_CORE(B) KEYS_P1 }
    __syncthreads();

    // tau search: wave w handles queries 2w, 2w+1 (16-bit count-select)
    #pragma unroll
    for (int e = 0; e < 2; ++e) {
        const int q2 = w * 2 + e;
        unsigned short vv[32];
        #pragma unroll
        for (int u = 0; u < 32; ++u) vv[u] = smp[q2 * SMPS + lane + u * 64];
        unsigned lo = 0;
        #pragma unroll
        for (int bit = 15; bit >= 0; --bit) {
            const unsigned trial = lo | (1u << bit);
            int c = 0;
            #pragma unroll
            for (int u = 0; u < 32; ++u) c += (vv[u] < trial);
            #pragma unroll
            for (int o = 32; o >= 1; o >>= 1) c += __shfl_xor(c, o);
            if (c < KK) lo = trial;
        }
        const float tf = (lo >= 0xFFFFu) ? __builtin_inff()
                                         : dec32((lo + 1u) << 16);
        if (lane == 0) tau_f[q2] = tf;
    }
    __syncthreads();   // smp dead after this; buffers take over the pool

    // ================= phase 2: full scan, append candidates ==============
    const float tauR = tau_f[q];
    {
        const int ncw = (NCH - w + NW - 1) / NW;   // chunks for this wave
        const int n2  = ncw * 4;                   // subtiles (156 or 160, even)
        LOAD_SUB(A, w, 0)
        LOAD_SUB(B, w, 1)
        for (int i = 0; i + 3 < n2; i += 2) {
            { MFMA_CORE(A) GATE_P2 }
            { const int ii = i + 2; LOAD_SUB(A, w + (ii >> 2) * NW, ii & 3) }
            { MFMA_CORE(B) GATE_P2 }
            { const int ii = i + 3; LOAD_SUB(B, w + (ii >> 2) * NW, ii & 3) }
        }
        { MFMA_CORE(A) GATE_P2 }
        { MFMA_CORE(B) GATE_P2 }
    }
    __syncthreads();

    // ================= phase 3: exact rank + weighted sum =================
    #pragma unroll
    for (int e = 0; e < 2; ++e) {
        const int q3 = w * 2 + e;
        const int n  = min(cnt[q3], CAP);
        const float qnv = qn[qbase + q3];

        float    ms[12]; unsigned kk[12]; unsigned short miu[12];
        #pragma unroll
        for (int u = 0; u < 12; ++u) {
            const int j = lane + u * 64;
            const bool v = (j < n);
            ms[u]  = v ? bufd[q3 * CAP + j] : __builtin_inff();
            miu[u] = v ? bufi[q3 * CAP + j] : (unsigned short)0xFFFFu;
            kk[u]  = enc32(ms[u]);
        }
        unsigned lo = 0;
        for (int bit = 31; bit >= 0; --bit) {
            const unsigned trial = lo | (1u << bit);
            int c = 0;
            #pragma unroll
            for (int u = 0; u < 12; ++u) c += (kk[u] < trial);
            #pragma unroll
            for (int o = 32; o >= 1; o >>= 1) c += __shfl_xor(c, o);
            if (c < KK) lo = trial;
        }
        int c0 = 0, tcnt = 0;
        #pragma unroll
        for (int u = 0; u < 12; ++u) { c0 += (kk[u] < lo); tcnt += (kk[u] == lo); }
        #pragma unroll
        for (int o = 32; o >= 1; o >>= 1) {
            c0 += __shfl_xor(c0, o); tcnt += __shfl_xor(tcnt, o);
        }
        const int kprime = KK - c0;
        unsigned ilo = 0xFFFFu;
        if (tcnt != kprime) {
            ilo = 0;
            for (int bit = 15; bit >= 0; --bit) {
                const unsigned trial = ilo | (1u << bit);
                int c = 0;
                #pragma unroll
                for (int u = 0; u < 12; ++u)
                    c += ((kk[u] == lo) && ((unsigned)miu[u] < trial));
                #pragma unroll
                for (int o = 32; o >= 1; o >>= 1) c += __shfl_xor(c, o);
                if (c < kprime) ilo = trial;
            }
        }
        float nume = 0.f, deno = 0.f;
        #pragma unroll
        for (int u = 0; u < 12; ++u) {
            const bool inc = (kk[u] < lo) ||
                             ((kk[u] == lo) && ((unsigned)miu[u] <= ilo));
            if (inc) {
                const float d2 = fmaxf(qnv + ms[u], 0.f);
                const float wv = 1.f / (d2 + 1e-4f);
                nume = fmaf(wv, targets[miu[u]], nume);
                deno += wv;
            }
        }
        #pragma unroll
        for (int o = 32; o >= 1; o >>= 1) {
            nume += __shfl_xor(nume, o);
            deno += __shfl_xor(deno, o);
        }
        if (lane == 0) out[qbase + q3] = nume / fmaxf(deno, 1e-9f);
    }
}

// ---------------- fallback: round-1 exact fp32 vector kernel ----------------
#define BQ 32
#define WQ 8
__global__ __launch_bounds__(256) void hp_knn_kernel(
    const float* __restrict__ points, const float* __restrict__ features,
    const float* __restrict__ targets, float* __restrict__ out)
{
    __shared__ __align__(16) float Qs[BQ][DD];
    __shared__ float qn_s[BQ];
    __shared__ float topd[BQ][KK];
    __shared__ int   topi[BQ][KK];
    const int tid = threadIdx.x, lane = tid & 63, wv = tid >> 6, qb = wv * WQ;
    {
        const float4* src = (const float4*)(points + (size_t)blockIdx.x * BQ * DD);
        float4* dst = (float4*)&Qs[0][0];
        #pragma unroll
        for (int i = 0; i < (BQ * DD / 4) / 256; ++i) dst[tid + i * 256] = src[tid + i * 256];
    }
    for (int i = tid; i < BQ * KK; i += 256) { (&topd[0][0])[i] = __builtin_inff(); (&topi[0][0])[i] = 0; }
    __syncthreads();
    if (tid < BQ) {
        float s = 0.f;
        #pragma unroll
        for (int d = 0; d < DD; ++d) s = fmaf(Qs[tid][d], Qs[tid][d], s);
        qn_s[tid] = s;
    }
    __syncthreads();
    for (int c = 0; c < (MM + 63) / 64; ++c) {
        const int m = c * 64 + lane, mc = (m < MM) ? m : (MM - 1);
        float f[DD];
        const float4* fr = (const float4*)(features + (size_t)mc * DD);
        #pragma unroll
        for (int b = 0; b < DD / 4; ++b) { float4 v = fr[b]; f[4*b]=v.x; f[4*b+1]=v.y; f[4*b+2]=v.z; f[4*b+3]=v.w; }
        float fnv = 0.f;
        #pragma unroll
        for (int d = 0; d < DD; ++d) fnv = fmaf(f[d], f[d], fnv);
        float d2v[WQ];
        #pragma unroll
        for (int qi = 0; qi < WQ; ++qi) {
            const float4* qr = (const float4*)&Qs[qb + qi][0];
            float a0=0,a1=0,a2=0,a3=0;
            #pragma unroll
            for (int b = 0; b < DD / 4; ++b) {
                float4 q4 = qr[b];
                a0 = fmaf(q4.x, f[4*b], a0); a1 = fmaf(q4.y, f[4*b+1], a1);
                a2 = fmaf(q4.z, f[4*b+2], a2); a3 = fmaf(q4.w, f[4*b+3], a3);
            }
            float d2 = fmaxf(qn_s[qb+qi] + fnv - 2.f*((a0+a1)+(a2+a3)), 0.f);
            d2v[qi] = (m < MM) ? d2 : __builtin_inff();
        }
        #pragma unroll
        for (int qi = 0; qi < WQ; ++qi) {
            const int q = qb + qi;
            unsigned long long ball = __ballot(d2v[qi] < topd[q][KK-1]);
            while (ball) {
                const int j = __builtin_ctzll(ball); ball &= ball - 1;
                const float dval = __shfl(d2v[qi], j); const int mval = c * 64 + j;
                if (lane < KK) {
                    const float cur = topd[q][lane];
                    if (cur > dval) {
                        const float pd = (lane > 0) ? topd[q][lane-1] : -1.f;
                        const int   pi = (lane > 0) ? topi[q][lane-1] : 0;
                        const bool tp = (pd > dval);
                        topd[q][lane] = tp ? pd : dval; topi[q][lane] = tp ? pi : mval;
                    }
                }
            }
        }
    }
    #pragma unroll
    for (int qi = 0; qi < WQ; ++qi) {
        const int q = qb + qi;
        float wsum = 0.f, wt = 0.f;
        if (lane < KK) {
            const float ww = 1.f / (topd[q][lane] + 1e-4f);
            wsum = ww; wt = ww * targets[topi[q][lane]];
        }
        #pragma unroll
        for (int o = 32; o >= 1; o >>= 1) { wsum += __shfl_xor(wsum, o); wt += __shfl_xor(wt, o); }
        if (lane == 0) out[(size_t)blockIdx.x * BQ + q] = wt / fmaxf(wsum, 1e-9f);
    }
}

extern "C" void kernel_launch(void* const* d_in, const int* in_sizes, int n_in,
                              void* d_out, int out_size, void* d_ws, size_t ws_size,
                              hipStream_t stream) {
    const float* points   = (const float*)d_in[0];
    const float* features = (const float*)d_in[1];
    const float* targets  = (const float*)d_in[2];
    float* out = (float*)d_out;

    if (ws_size < (size_t)WS_REQ) {
        hp_knn_kernel<<<dim3(NQ / BQ), dim3(256), 0, stream>>>(points, features, targets, out);
        return;
    }
    char* ws = (char*)d_ws;
    unsigned short* Fh = (unsigned short*)(ws + OFF_FH);
    unsigned short* Fl = (unsigned short*)(ws + OFF_FL);
    float*          fn = (float*)(ws + OFF_FN);
    unsigned short* Qh = (unsigned short*)(ws + OFF_QH);
    unsigned short* Ql = (unsigned short*)(ws + OFF_QL);
    float*          qnp= (float*)(ws + OFF_QN);

    prep_split<<<dim3(MPAD * DD / 256), dim3(256), 0, stream>>>(features, Fh, Fl, fn, MM);
    prep_split<<<dim3(NQ * DD / 256),  dim3(256), 0, stream>>>(points,   Qh, Ql, qnp, NQ);
    knn_filter<<<dim3(NQ / 16), dim3(512), 0, stream>>>(Fh, Fl, fn, Qh, Ql, qnp, targets, out);
}